// Round 16
// baseline (113.847 us; speedup 1.0000x reference)
//
#include <hip/hip_runtime.h>
#include <hip/hip_bf16.h>
#include <stdint.h>
#include <stddef.h>

typedef __bf16 bf16_t;
typedef __bf16 bf16x8 __attribute__((ext_vector_type(8)));
typedef __bf16 bf16x4 __attribute__((ext_vector_type(4)));
typedef float  f32x4  __attribute__((ext_vector_type(4)));

#define NB 8192
#define ND 512
#define NH 2048
#define NHV 512
#define NVO 256
#define RF_TOL 1e-3f
#define NEWTON_MAX 16

typedef const __attribute__((address_space(1))) void gvoid_t;
typedef __attribute__((address_space(3))) void lvoid_t;

__device__ __forceinline__ void gload_lds16(const void* g, void* l) {
  __builtin_amdgcn_global_load_lds((gvoid_t*)g, (lvoid_t*)l, 16, 0, 0);
}

__device__ __forceinline__ float fast_tanhf(float x) {
  x = fminf(fmaxf(x, -15.0f), 15.0f);
  float e = __expf(2.0f * x);
  return (e - 1.0f) * __builtin_amdgcn_rcpf(e + 1.0f);
}

struct GJob {
  const bf16_t* A;    // [8192][K] row-major bf16
  const bf16_t* Bt;   // [N][K] row-major bf16 (pre-transposed B)
  const float*  bias; // [N] or null
  bf16_t* Cbf;        // [8192][N] or null
  float*  Cf;         // [8192][N] or null
  float*  rowsq;      // [8192] or null: atomicAdd per-row sum(v^2) (no C write)
  int N, K, nbx, tanh_act;
};

// ------------------ transpose tile body (shared) ----------------------------
__device__ __forceinline__ void tr_body(const float* __restrict__ src, bf16_t* __restrict__ dst,
                                        int R, int C, int bidx, float (*tile)[33]) {
  const int tilesx = C >> 5;
  const int bi = (bidx / tilesx) << 5, bj = (bidx % tilesx) << 5;
  const int t = threadIdx.x, tx = t & 31, ty = t >> 5;
#pragma unroll
  for (int r = ty; r < 32; r += 8)
    tile[r][tx] = src[(size_t)(bi + r) * C + (bj + tx)];
  __syncthreads();
#pragma unroll
  for (int r = ty; r < 32; r += 8)
    dst[(size_t)(bj + r) * R + (bi + tx)] = (bf16_t)tile[tx][r];
}

// ---- dual-job GEMM: BMx128 tile, BK=64, single-buffer (m97 structure) ------
// r3/r7/r8-proven loop + XCD swizzle. GEMM-loop lever closed (r8). r10/r13
// lesson (twice): work is cheap where it OVERLAPS, expensive where it
// serializes. TBX>0 reserves bx cols [TBX,gridDim.x) for W2/Wv2 transpose
// freeloaders; r15 measured the slot-count lever (1152->576 slots: -0.9us);
// r16: 4 consecutive tiles/block -> 320 slots in 5 cols (tt<1152 guard, 32
// blocks idle). Consecutive tiles share the 32-row source panel (L2 hits);
// per-block ~5us << one GEMM residency round (~24us) so never critical-tail.
// rowsq jobs (jy) atomicAdd per-row sum(v^2) instead of writing C. r12: jf's
// Cf points DIRECTLY at d_out (out==fhat until newton scales alpha!=1 rows).
template<int BM, bool SWZ, int TBX>
__global__ __launch_bounds__(256, 4)
void gemm_kernel(GJob j0, GJob j1,
                 const float* tw2, bf16_t* tw2t, const float* twv2, bf16_t* twv2t)
{
  constexpr int MI = BM / 32;          // A-frags (16-row) per wave half
  __shared__ bf16_t As[BM * 64];       // BM x 128B
  __shared__ bf16_t Bs[128 * 64];      // 16KB

  int bx0, by;
  if (SWZ) {
    int f = (int)blockIdx.y * (int)gridDim.x + (int)blockIdx.x;
    const int nwg = (int)gridDim.x * (int)gridDim.y;   // divisible by 8
    f = (f & 7) * (nwg >> 3) + (f >> 3);
    bx0 = f % (int)gridDim.x;
    by  = f / (int)gridDim.x;
  } else {
    bx0 = (int)blockIdx.x;
    by  = (int)blockIdx.y;
  }

  if (TBX > 0 && bx0 >= TBX) {         // transpose freeloader blocks (G1 only)
    float (*tile)[33] = reinterpret_cast<float(*)[33]>(As);
    const int idx = (bx0 - TBX) * (int)gridDim.y + by;   // [0, 320)
    for (int q = 0; q < 4; ++q) {
      const int tt = idx * 4 + q;                        // [0, 1280)
      if (tt >= 1152) break;                             // uniform: safe w/ barriers
      if (tt < 1024) tr_body(tw2, tw2t, 2048, 512, tt, tile);
      else           tr_body(twv2, twv2t, 512, 256, tt - 1024, tile);
      __syncthreads();                 // tile buffer reuse between passes
    }
    return;
  }

  const bool first = bx0 < j0.nbx;
  const GJob jb = first ? j0 : j1;
  const int bx = bx0 - (first ? 0 : j0.nbx);
  const int K = jb.K, N = jb.N;

  const int t = threadIdx.x, lane = t & 63, w = t >> 6;
  const int wm = w >> 1, wn = w & 1;
  const int la = lane & 15, lg = lane >> 4;
  const size_t m0 = (size_t)by * BM, n0 = (size_t)bx * 128;

  size_t soffA[MI], soffB[4]; int doff[4];
#pragma unroll
  for (int j = 0; j < 4; ++j) {
    const int off = t * 16 + j * 4096;
    const int r = off >> 7, c = off & 127;
    const size_t so = (size_t)r * K + ((c ^ ((r & 7) << 4)) >> 1);  // pre-swizzled
    if (j < MI) soffA[j] = so;
    soffB[j] = so;
    doff[j] = off;
  }
  const bf16_t* Ab = jb.A + m0 * K;
  const bf16_t* Bb = jb.Bt + n0 * K;

  int abyte[MI][2], bbyte[4][2];
#pragma unroll
  for (int ks = 0; ks < 2; ++ks) {
#pragma unroll
    for (int i = 0; i < MI; ++i) {
      const int ra = wm * (BM / 2) + i * 16 + la;
      abyte[i][ks] = ra * 128 + ((ks * 64 + lg * 16) ^ ((ra & 7) << 4));
    }
#pragma unroll
    for (int j = 0; j < 4; ++j) {
      const int rb = wn * 64 + j * 16 + la;
      bbyte[j][ks] = rb * 128 + ((ks * 64 + lg * 16) ^ ((rb & 7) << 4));
    }
  }

  f32x4 acc[MI][4] = {};
  const int nsteps = K >> 6;

  for (int ts = 0; ts < nsteps; ++ts) {
    const int k0 = ts << 6;
#pragma unroll
    for (int j = 0; j < MI; ++j)
      gload_lds16(Ab + soffA[j] + k0, (char*)As + doff[j]);
#pragma unroll
    for (int j = 0; j < 4; ++j)
      gload_lds16(Bb + soffB[j] + k0, (char*)Bs + doff[j]);
    __syncthreads();

    bf16x8 afr[MI][2], bfr[4][2];
#pragma unroll
    for (int ks = 0; ks < 2; ++ks) {
#pragma unroll
      for (int i = 0; i < MI; ++i)
        afr[i][ks] = *(const bf16x8*)((const char*)As + abyte[i][ks]);
#pragma unroll
      for (int j = 0; j < 4; ++j)
        bfr[j][ks] = *(const bf16x8*)((const char*)Bs + bbyte[j][ks]);
    }
#pragma unroll
    for (int ks = 0; ks < 2; ++ks)
#pragma unroll
      for (int i = 0; i < MI; ++i)
#pragma unroll
        for (int j = 0; j < 4; ++j)
          acc[i][j] = __builtin_amdgcn_mfma_f32_16x16x32_bf16(afr[i][ks], bfr[j][ks], acc[i][j], 0, 0, 0);
    __syncthreads();
  }

  // epilogue (runtime flags; all uniform branches)
  if (jb.rowsq) {
#pragma unroll
    for (int i = 0; i < MI; ++i) {
#pragma unroll
      for (int r = 0; r < 4; ++r) {
        float s = 0.0f;
#pragma unroll
        for (int j = 0; j < 4; ++j) { float v = acc[i][j][r]; s = fmaf(v, v, s); }
        s += __shfl_xor(s, 1); s += __shfl_xor(s, 2);
        s += __shfl_xor(s, 4); s += __shfl_xor(s, 8);
        if (la == 0)
          atomicAdd(&jb.rowsq[m0 + wm * (BM / 2) + i * 16 + lg * 4 + r], s);
      }
    }
    return;
  }
#pragma unroll
  for (int i = 0; i < MI; ++i) {
#pragma unroll
    for (int j = 0; j < 4; ++j) {
      const size_t col = n0 + wn * 64 + j * 16 + la;
      const float bv = jb.bias ? jb.bias[col] : 0.0f;
#pragma unroll
      for (int r = 0; r < 4; ++r) {
        const size_t row = m0 + wm * (BM / 2) + i * 16 + lg * 4 + r;
        float v = acc[i][j][r] + bv;
        if (jb.tanh_act) v = fast_tanhf(v);
        if (jb.Cbf) jb.Cbf[row * N + col] = (bf16_t)v;
        if (jb.Cf)  jb.Cf [row * N + col] = v;
      }
    }
  }
}

// ------ fused prep: W1,Wv1 transposes + rowcast(x) + zero yxsq --------------
__global__ void prep_kernel(const float* __restrict__ x, bf16_t* __restrict__ xbf, float* __restrict__ xsq,
                            const float* __restrict__ W1, bf16_t* __restrict__ w1t,
                            const float* __restrict__ Wv1, bf16_t* __restrict__ wv1t,
                            float* __restrict__ yxsq)
{
  __shared__ float tile[32][33];
  const int b = blockIdx.x;
  if (b < 1024)      tr_body(W1, w1t, 512, 2048, b, tile);
  else if (b < 1280) tr_body(Wv1, wv1t, 512, 512, b - 1024, tile);
  else {
    const int t = threadIdx.x;
    const int row = (b - 1280) * 4 + (t >> 6), l = t & 63;
    const float4* sr = (const float4*)(x + (size_t)row * ND);
    bf16x4* dw = (bf16x4*)(xbf + (size_t)row * ND);
    float s = 0.0f;
#pragma unroll
    for (int c = l; c < ND / 4; c += 64) {
      float4 v = sr[c];
      s = fmaf(v.x, v.x, fmaf(v.y, v.y, fmaf(v.z, v.z, fmaf(v.w, v.w, s))));
      bf16x4 o;
      o[0] = (bf16_t)v.x; o[1] = (bf16_t)v.y; o[2] = (bf16_t)v.z; o[3] = (bf16_t)v.w;
      dw[c] = o;
    }
#pragma unroll
    for (int m = 32; m; m >>= 1) s += __shfl_xor(s, m);
    if (l == 0) xsq[row] = s;
    if (l == 1) yxsq[row] = 0.0f;   // zero the G2 sumsq accumulator
  }
}

// ------------- fused Newton: u0-GEMM + fsq/tgt + root-find + scale ----------
// r11 null-result: for this data resid<=TOL at it=0 for ~all samples -> alpha
// stays exactly 1 and the loop is a single check. r12 exploits that: G2 wrote
// fhat DIRECTLY into out; here only rows whose alpha moved off 1.0 (exact
// compare — alpha is written only under `go`) are scaled IN PLACE. alpha==1
// rows keep out==fhat bitwise-identical to the old fhat*1.0f path.
__global__ __launch_bounds__(512, 1)
void newton_kernel(const bf16_t* __restrict__ fbf, const bf16_t* __restrict__ wv1t,
                   const bf16_t* __restrict__ Wv2t,
                   const float* __restrict__ yxsq, const float* __restrict__ xsq,
                   float* __restrict__ out)
{
  __shared__ alignas(16) bf16_t hs[32 * 512];   // 32KB, XOR-swizzled
  __shared__ alignas(16) bf16_t es[32 * 512];
  __shared__ float red[8][32][2];
  __shared__ float alpha_s[32], fsq_s[32], tgt_s[32];
  __shared__ int notdone_s;

  const int t = threadIdx.x, lane = t & 63, w = t >> 6;
  const int la = lane & 15, lg = lane >> 4;
  const int s_base = blockIdx.x * 32;
  const int arow = lane & 31, ahi = lane >> 5;

  // ---- P0: fbf -> hs (swizzled) + fsq; 16 threads per row
  {
    const int row = t >> 4, c0 = (t & 15) * 4;
    float s = 0.0f;
#pragma unroll
    for (int i = 0; i < 4; ++i) {
      const int k8 = c0 + i;
      bf16x8 v = *(const bf16x8*)(fbf + (size_t)(s_base + row) * ND + k8 * 8);
#pragma unroll
      for (int q = 0; q < 8; ++q) { float f = (float)v[q]; s = fmaf(f, f, s); }
      *(bf16x8*)((char*)hs + (row << 10) + ((k8 ^ (row & 7)) << 4)) = v;
    }
    s += __shfl_xor(s, 1); s += __shfl_xor(s, 2); s += __shfl_xor(s, 4); s += __shfl_xor(s, 8);
    if ((t & 15) == 0) fsq_s[row] = s;
  }
  if (t < 32) {
    alpha_s[t] = 1.0f;
    tgt_s[t] = 0.99f * (yxsq[s_base + t] + 0.01f * xsq[s_base + t]);
  }
  __syncthreads();

  // ---- P1: u0 = fbf @ Wv1; wave w owns HV cols [w*64, w*64+64)
  f32x4 uacc[2][4] = {};   // [mt][nt]
#pragma unroll
  for (int k = 0; k < 16; ++k) {
    bf16x8 afr[2];
#pragma unroll
    for (int mt = 0; mt < 2; ++mt) {
      const int row = mt * 16 + la;
      afr[mt] = *(const bf16x8*)((const char*)hs + (row << 10) + (((k * 4 + lg) ^ (row & 7)) << 4));
    }
#pragma unroll
    for (int nt = 0; nt < 4; ++nt) {
      const bf16x8 b = *(const bf16x8*)(wv1t + (size_t)(w * 64 + nt * 16 + la) * ND + k * 32 + lg * 8);
#pragma unroll
      for (int mt = 0; mt < 2; ++mt)
        uacc[mt][nt] = __builtin_amdgcn_mfma_f32_16x16x32_bf16(afr[mt], b, uacc[mt][nt], 0, 0, 0);
    }
  }

  // ---- P2: deposit u0 -> es in [row][k8] XOR layout (C: col=la, row=lg*4+r)
#pragma unroll
  for (int mt = 0; mt < 2; ++mt)
#pragma unroll
    for (int nt = 0; nt < 4; ++nt)
#pragma unroll
      for (int r = 0; r < 4; ++r) {
        const int row = mt * 16 + lg * 4 + r;
        const int col = w * 64 + nt * 16 + la;
        *(bf16_t*)((char*)es + (row << 10) + (((col >> 3) ^ (row & 7)) << 4) + (col & 7) * 2)
            = (bf16_t)uacc[mt][nt][r];
      }
  __syncthreads();

  // ureg from es (phase-A ownership: row=arow, chunks k8 = w*8+ahi*4+i)
  bf16x8 ureg[4];
#pragma unroll
  for (int i = 0; i < 4; ++i) {
    const int k8 = w * 8 + ahi * 4 + i;
    ureg[i] = *(const bf16x8*)((const char*)es + (arow << 10) + ((k8 ^ (arow & 7)) << 4));
  }

  // Wv2t B-frags -> registers (after u0 phase to keep peak VGPR low)
  bf16x8 bfr[2][16];
#pragma unroll
  for (int nt = 0; nt < 2; ++nt) {
    const bf16_t* bp = Wv2t + (size_t)(w * 32 + nt * 16 + la) * NHV + lg * 8;
#pragma unroll
    for (int k = 0; k < 16; ++k)
      bfr[nt][k] = *(const bf16x8*)(bp + k * 32);
  }
  __syncthreads();   // all ureg reads of es done before phase-A overwrites it

  for (int it = 0; it < NEWTON_MAX; ++it) {
    // ---- phase A: tanh from registers -> swizzled LDS
    {
      const float c2 = 2.0f * alpha_s[arow];
#pragma unroll
      for (int i = 0; i < 4; ++i) {
        const int k8 = w * 8 + ahi * 4 + i;
        const int byte = (arow << 10) + ((k8 ^ (arow & 7)) << 4);
        bf16x8 uv = ureg[i], hf, ef;
#pragma unroll
        for (int q = 0; q < 8; ++q) {
          float u = (float)uv[q];
          float e = __expf(c2 * u);
          float h = (e - 1.0f) * __builtin_amdgcn_rcpf(e + 1.0f);
          hf[q] = (bf16_t)h;
          ef[q] = (bf16_t)(u * (1.0f - h * h));
        }
        *(bf16x8*)((char*)hs + byte) = hf;
        *(bf16x8*)((char*)es + byte) = ef;
      }
    }
    __syncthreads();

    // ---- phase B: MFMA with register-resident B
    f32x4 accy[2][2] = {};
    f32x4 accw[2][2] = {};
#pragma unroll
    for (int k = 0; k < 16; ++k) {
#pragma unroll
      for (int mt = 0; mt < 2; ++mt) {
        const int row = mt * 16 + la;
        const int byte = (row << 10) + (((k * 4 + lg) ^ (row & 7)) << 4);
        bf16x8 hf = *(const bf16x8*)((const char*)hs + byte);
        bf16x8 ef = *(const bf16x8*)((const char*)es + byte);
#pragma unroll
        for (int nt = 0; nt < 2; ++nt) {
          accy[mt][nt] = __builtin_amdgcn_mfma_f32_16x16x32_bf16(hf, bfr[nt][k], accy[mt][nt], 0, 0, 0);
          accw[mt][nt] = __builtin_amdgcn_mfma_f32_16x16x32_bf16(ef, bfr[nt][k], accw[mt][nt], 0, 0, 0);
        }
      }
    }

    // ---- reduce: SY = sum y^2, SW = sum y*w  (C layout: col=la, row=lg*4+r)
#pragma unroll
    for (int mt = 0; mt < 2; ++mt) {
#pragma unroll
      for (int r = 0; r < 4; ++r) {
        float sy = 0.0f, sw = 0.0f;
#pragma unroll
        for (int nt = 0; nt < 2; ++nt) {
          float yv = accy[mt][nt][r], wv = accw[mt][nt][r];
          sy = fmaf(yv, yv, sy);
          sw = fmaf(yv, wv, sw);
        }
        sy += __shfl_xor(sy, 1); sw += __shfl_xor(sw, 1);
        sy += __shfl_xor(sy, 2); sw += __shfl_xor(sw, 2);
        sy += __shfl_xor(sy, 4); sw += __shfl_xor(sw, 4);
        sy += __shfl_xor(sy, 8); sw += __shfl_xor(sw, 8);
        if (la == 0) {
          red[w][mt * 16 + lg * 4 + r][0] = sy;
          red[w][mt * 16 + lg * 4 + r][1] = sw;
        }
      }
    }
    __syncthreads();
    if (t < 32) {
      float SY = 0.0f, SW = 0.0f;
#pragma unroll
      for (int w8 = 0; w8 < 8; ++w8) {
        SY += red[w8][t][0];
        SW += red[w8][t][1];
      }
      float a = alpha_s[t];
      const float fs = fsq_s[t];
      const float V = SY + 0.01f * a * a * fs;
      const float dV = 2.0f * SW + 0.02f * a * fs;
      const float resid = V - tgt_s[t];
      const bool go = resid > RF_TOL;
      if (go) {
        if (it == 0)
          alpha_s[t] = __builtin_sqrtf(tgt_s[t] / V);  // quadratic-model root (a==1, V==V1)
        else
          alpha_s[t] = a - resid / dV;                 // ref's Newton step
      }
      const int nd = __any(go);
      if (t == 0) notdone_s = nd;
    }
    __syncthreads();
    if (!notdone_s) break;                   // all converged: further iters no-op
  }

  // ---- conditional in-place scale: only alpha!=1 rows touch memory.
  // alpha==1 rows: out already holds fhat (G2 wrote it) == fhat*1.0f exactly.
  {
    const int r = t >> 4;
    const int c4 = t & 15;
    const float a = alpha_s[r];
    if (a != 1.0f) {
      const size_t rb = (size_t)(s_base + r) * ND;
      float4* dp = (float4*)(out + rb);
#pragma unroll
      for (int jj = 0; jj < 8; ++jj) {
        float4 v = dp[c4 + jj * 16];
        v.x *= a; v.y *= a; v.z *= a; v.w *= a;
        dp[c4 + jj * 16] = v;
      }
    }
  }
}

extern "C" void kernel_launch(void* const* d_in, const int* in_sizes, int n_in,
                              void* d_out, int out_size, void* d_ws, size_t ws_size,
                              hipStream_t stream)
{
  (void)in_sizes; (void)n_in; (void)out_size; (void)ws_size;
  const float* x   = (const float*)d_in[0];
  const float* W1  = (const float*)d_in[1];
  const float* b1  = (const float*)d_in[2];
  const float* W2  = (const float*)d_in[3];
  const float* b2  = (const float*)d_in[4];
  const float* Wv1 = (const float*)d_in[5];
  const float* Wv2 = (const float*)d_in[6];
  float* out = (float*)d_out;

  char* ws = (char*)d_ws;
  size_t off = 0;
  auto alloc = [&](size_t n) { char* p = ws + off; off += (n + 255) & ~(size_t)255; return p; };

  bf16_t* xbf  = (bf16_t*)alloc((size_t)NB * ND * 2);
  bf16_t* w1t  = (bf16_t*)alloc((size_t)NH * ND * 2);
  bf16_t* w2t  = (bf16_t*)alloc((size_t)ND * NH * 2);
  bf16_t* wv1t = (bf16_t*)alloc((size_t)NHV * ND * 2);
  bf16_t* wv2t = (bf16_t*)alloc((size_t)NVO * NHV * 2);
  bf16_t* h1   = (bf16_t*)alloc((size_t)NB * NH * 2);
  bf16_t* fbf  = (bf16_t*)alloc((size_t)NB * ND * 2);
  bf16_t* hx   = (bf16_t*)alloc((size_t)NB * NHV * 2);
  float*  xsq  = (float*)alloc((size_t)NB * 4);
  float*  yxsq = (float*)alloc((size_t)NB * 4);

  // 1. prep: W1,Wv1 transpose+cast (1280 blocks) + x rowcast + yxsq zero (2048)
  prep_kernel<<<3328, 256, 0, stream>>>(x, xbf, xsq, W1, w1t, Wv1, wv1t, yxsq);

  // 2. G1: h1 = tanh(x@W1+b1) [16 bx] + hx = tanh(x@Wv1) [4 bx]
  //    + 5 bx columns of W2/Wv2 transpose freeloaders (320 blocks x 4 tiles)
  //    grid (25, 64) = 1600 blocks, %8==0 -> bijective XCD swizzle
  GJob jh1 { xbf, w1t,  b1,      h1,  nullptr, nullptr, NH,  ND, NH  / 128, 1 };
  GJob jhx { xbf, wv1t, nullptr, hx,  nullptr, nullptr, NHV, ND, NHV / 128, 1 };
  gemm_kernel<128, true, 20><<<dim3(25, NB / 128), 256, 0, stream>>>(jh1, jhx, W2, w2t, Wv2, wv2t);

  // 3. G2: {fbf(bf16), out(f32)} = h1@W2+b2 + yxsq += rowsumsq(hx@Wv2)
  //    out doubles as fhat: newton scales only alpha!=1 rows in place.
  GJob jf  { h1,  w2t,  b2,      fbf, out,     nullptr, ND,  NH, ND  / 128, 0 };
  GJob jy  { hx,  wv2t, nullptr, nullptr, nullptr, yxsq, NVO, NHV, NVO / 128, 0 };
  gemm_kernel<64, true, 0><<<dim3(ND / 128 + NVO / 128, NB / 64), 256, 0, stream>>>(jf, jy, nullptr, nullptr, nullptr, nullptr);

  // 4. fused Newton: u0-GEMM + fsq/tgt + root-find + conditional in-place scale
  newton_kernel<<<NB / 32, 512, 0, stream>>>(fbf, wv1t, wv2t, yxsq, xsq, out);
}

// Round 17
// 110.120 us; speedup vs baseline: 1.0338x; 1.0338x over previous
//
#include <hip/hip_runtime.h>
#include <hip/hip_bf16.h>
#include <stdint.h>
#include <stddef.h>

typedef __bf16 bf16_t;
typedef __bf16 bf16x8 __attribute__((ext_vector_type(8)));
typedef __bf16 bf16x4 __attribute__((ext_vector_type(4)));
typedef float  f32x4  __attribute__((ext_vector_type(4)));

#define NB 8192
#define ND 512
#define NH 2048
#define NHV 512
#define NVO 256
#define RF_TOL 1e-3f
#define NEWTON_MAX 16

typedef const __attribute__((address_space(1))) void gvoid_t;
typedef __attribute__((address_space(3))) void lvoid_t;

__device__ __forceinline__ void gload_lds16(const void* g, void* l) {
  __builtin_amdgcn_global_load_lds((gvoid_t*)g, (lvoid_t*)l, 16, 0, 0);
}

__device__ __forceinline__ float fast_tanhf(float x) {
  x = fminf(fmaxf(x, -15.0f), 15.0f);
  float e = __expf(2.0f * x);
  return (e - 1.0f) * __builtin_amdgcn_rcpf(e + 1.0f);
}

struct GJob {
  const bf16_t* A;    // [8192][K] row-major bf16
  const bf16_t* Bt;   // [N][K] row-major bf16 (pre-transposed B)
  const float*  bias; // [N] or null
  bf16_t* Cbf;        // [8192][N] or null
  float*  Cf;         // [8192][N] or null
  float*  rowsq;      // [8192] or null: atomicAdd per-row sum(v^2) (no C write)
  int N, K, nbx, tanh_act;
};

// ------------------ transpose tile body (shared) ----------------------------
__device__ __forceinline__ void tr_body(const float* __restrict__ src, bf16_t* __restrict__ dst,
                                        int R, int C, int bidx, float (*tile)[33]) {
  const int tilesx = C >> 5;
  const int bi = (bidx / tilesx) << 5, bj = (bidx % tilesx) << 5;
  const int t = threadIdx.x, tx = t & 31, ty = t >> 5;
#pragma unroll
  for (int r = ty; r < 32; r += 8)
    tile[r][tx] = src[(size_t)(bi + r) * C + (bj + tx)];
  __syncthreads();
#pragma unroll
  for (int r = ty; r < 32; r += 8)
    dst[(size_t)(bj + r) * R + (bi + tx)] = (bf16_t)tile[tx][r];
}

// ---- dual-job GEMM: BMx128 tile, BK=64, single-buffer (m97 structure) ------
// r3/r7/r8-proven loop + XCD swizzle. GEMM-loop lever closed (r8). r10/r13
// lesson (twice): work is cheap where it OVERLAPS, expensive where it
// serializes. TBX>0 reserves bx cols [TBX,gridDim.x) for W2/Wv2 transpose
// freeloaders. Slot-count lever measured on both sides: 1152/576/320 slots ->
// 111.1/110.2/113.8 us; optimum = 576 (2 tiles/block, r15 config — 4/block
// doubles per-block time and the stragglers BECOME the tail). rowsq jobs (jy)
// atomicAdd per-row sum(v^2) instead of writing C. r12: jf's Cf points
// DIRECTLY at d_out (out==fhat until newton scales alpha!=1 rows in place).
template<int BM, bool SWZ, int TBX>
__global__ __launch_bounds__(256, 4)
void gemm_kernel(GJob j0, GJob j1,
                 const float* tw2, bf16_t* tw2t, const float* twv2, bf16_t* twv2t)
{
  constexpr int MI = BM / 32;          // A-frags (16-row) per wave half
  __shared__ bf16_t As[BM * 64];       // BM x 128B
  __shared__ bf16_t Bs[128 * 64];      // 16KB

  int bx0, by;
  if (SWZ) {
    int f = (int)blockIdx.y * (int)gridDim.x + (int)blockIdx.x;
    const int nwg = (int)gridDim.x * (int)gridDim.y;   // divisible by 8
    f = (f & 7) * (nwg >> 3) + (f >> 3);
    bx0 = f % (int)gridDim.x;
    by  = f / (int)gridDim.x;
  } else {
    bx0 = (int)blockIdx.x;
    by  = (int)blockIdx.y;
  }

  if (TBX > 0 && bx0 >= TBX) {         // transpose freeloader blocks (G1 only)
    float (*tile)[33] = reinterpret_cast<float(*)[33]>(As);
    const int idx = (bx0 - TBX) * (int)gridDim.y + by;   // [0, 576)
#pragma unroll
    for (int q = 0; q < 2; ++q) {
      const int tt = idx * 2 + q;                        // [0, 1152)
      if (tt < 1024) tr_body(tw2, tw2t, 2048, 512, tt, tile);
      else           tr_body(twv2, twv2t, 512, 256, tt - 1024, tile);
      __syncthreads();                 // tile buffer reuse between the 2 passes
    }
    return;
  }

  const bool first = bx0 < j0.nbx;
  const GJob jb = first ? j0 : j1;
  const int bx = bx0 - (first ? 0 : j0.nbx);
  const int K = jb.K, N = jb.N;

  const int t = threadIdx.x, lane = t & 63, w = t >> 6;
  const int wm = w >> 1, wn = w & 1;
  const int la = lane & 15, lg = lane >> 4;
  const size_t m0 = (size_t)by * BM, n0 = (size_t)bx * 128;

  size_t soffA[MI], soffB[4]; int doff[4];
#pragma unroll
  for (int j = 0; j < 4; ++j) {
    const int off = t * 16 + j * 4096;
    const int r = off >> 7, c = off & 127;
    const size_t so = (size_t)r * K + ((c ^ ((r & 7) << 4)) >> 1);  // pre-swizzled
    if (j < MI) soffA[j] = so;
    soffB[j] = so;
    doff[j] = off;
  }
  const bf16_t* Ab = jb.A + m0 * K;
  const bf16_t* Bb = jb.Bt + n0 * K;

  int abyte[MI][2], bbyte[4][2];
#pragma unroll
  for (int ks = 0; ks < 2; ++ks) {
#pragma unroll
    for (int i = 0; i < MI; ++i) {
      const int ra = wm * (BM / 2) + i * 16 + la;
      abyte[i][ks] = ra * 128 + ((ks * 64 + lg * 16) ^ ((ra & 7) << 4));
    }
#pragma unroll
    for (int j = 0; j < 4; ++j) {
      const int rb = wn * 64 + j * 16 + la;
      bbyte[j][ks] = rb * 128 + ((ks * 64 + lg * 16) ^ ((rb & 7) << 4));
    }
  }

  f32x4 acc[MI][4] = {};
  const int nsteps = K >> 6;

  for (int ts = 0; ts < nsteps; ++ts) {
    const int k0 = ts << 6;
#pragma unroll
    for (int j = 0; j < MI; ++j)
      gload_lds16(Ab + soffA[j] + k0, (char*)As + doff[j]);
#pragma unroll
    for (int j = 0; j < 4; ++j)
      gload_lds16(Bb + soffB[j] + k0, (char*)Bs + doff[j]);
    __syncthreads();

    bf16x8 afr[MI][2], bfr[4][2];
#pragma unroll
    for (int ks = 0; ks < 2; ++ks) {
#pragma unroll
      for (int i = 0; i < MI; ++i)
        afr[i][ks] = *(const bf16x8*)((const char*)As + abyte[i][ks]);
#pragma unroll
      for (int j = 0; j < 4; ++j)
        bfr[j][ks] = *(const bf16x8*)((const char*)Bs + bbyte[j][ks]);
    }
#pragma unroll
    for (int ks = 0; ks < 2; ++ks)
#pragma unroll
      for (int i = 0; i < MI; ++i)
#pragma unroll
        for (int j = 0; j < 4; ++j)
          acc[i][j] = __builtin_amdgcn_mfma_f32_16x16x32_bf16(afr[i][ks], bfr[j][ks], acc[i][j], 0, 0, 0);
    __syncthreads();
  }

  // epilogue (runtime flags; all uniform branches)
  if (jb.rowsq) {
#pragma unroll
    for (int i = 0; i < MI; ++i) {
#pragma unroll
      for (int r = 0; r < 4; ++r) {
        float s = 0.0f;
#pragma unroll
        for (int j = 0; j < 4; ++j) { float v = acc[i][j][r]; s = fmaf(v, v, s); }
        s += __shfl_xor(s, 1); s += __shfl_xor(s, 2);
        s += __shfl_xor(s, 4); s += __shfl_xor(s, 8);
        if (la == 0)
          atomicAdd(&jb.rowsq[m0 + wm * (BM / 2) + i * 16 + lg * 4 + r], s);
      }
    }
    return;
  }
#pragma unroll
  for (int i = 0; i < MI; ++i) {
#pragma unroll
    for (int j = 0; j < 4; ++j) {
      const size_t col = n0 + wn * 64 + j * 16 + la;
      const float bv = jb.bias ? jb.bias[col] : 0.0f;
#pragma unroll
      for (int r = 0; r < 4; ++r) {
        const size_t row = m0 + wm * (BM / 2) + i * 16 + lg * 4 + r;
        float v = acc[i][j][r] + bv;
        if (jb.tanh_act) v = fast_tanhf(v);
        if (jb.Cbf) jb.Cbf[row * N + col] = (bf16_t)v;
        if (jb.Cf)  jb.Cf [row * N + col] = v;
      }
    }
  }
}

// ------ fused prep: W1,Wv1 transposes + rowcast(x) + zero yxsq --------------
__global__ void prep_kernel(const float* __restrict__ x, bf16_t* __restrict__ xbf, float* __restrict__ xsq,
                            const float* __restrict__ W1, bf16_t* __restrict__ w1t,
                            const float* __restrict__ Wv1, bf16_t* __restrict__ wv1t,
                            float* __restrict__ yxsq)
{
  __shared__ float tile[32][33];
  const int b = blockIdx.x;
  if (b < 1024)      tr_body(W1, w1t, 512, 2048, b, tile);
  else if (b < 1280) tr_body(Wv1, wv1t, 512, 512, b - 1024, tile);
  else {
    const int t = threadIdx.x;
    const int row = (b - 1280) * 4 + (t >> 6), l = t & 63;
    const float4* sr = (const float4*)(x + (size_t)row * ND);
    bf16x4* dw = (bf16x4*)(xbf + (size_t)row * ND);
    float s = 0.0f;
#pragma unroll
    for (int c = l; c < ND / 4; c += 64) {
      float4 v = sr[c];
      s = fmaf(v.x, v.x, fmaf(v.y, v.y, fmaf(v.z, v.z, fmaf(v.w, v.w, s))));
      bf16x4 o;
      o[0] = (bf16_t)v.x; o[1] = (bf16_t)v.y; o[2] = (bf16_t)v.z; o[3] = (bf16_t)v.w;
      dw[c] = o;
    }
#pragma unroll
    for (int m = 32; m; m >>= 1) s += __shfl_xor(s, m);
    if (l == 0) xsq[row] = s;
    if (l == 1) yxsq[row] = 0.0f;   // zero the G2 sumsq accumulator
  }
}

// ------------- fused Newton: u0-GEMM + fsq/tgt + root-find + scale ----------
// r11 null-result: for this data resid<=TOL at it=0 for ~all samples -> alpha
// stays exactly 1 and the loop is a single check. r12 exploits that: G2 wrote
// fhat DIRECTLY into out; here only rows whose alpha moved off 1.0 (exact
// compare — alpha is written only under `go`) are scaled IN PLACE. alpha==1
// rows keep out==fhat bitwise-identical to the old fhat*1.0f path.
__global__ __launch_bounds__(512, 1)
void newton_kernel(const bf16_t* __restrict__ fbf, const bf16_t* __restrict__ wv1t,
                   const bf16_t* __restrict__ Wv2t,
                   const float* __restrict__ yxsq, const float* __restrict__ xsq,
                   float* __restrict__ out)
{
  __shared__ alignas(16) bf16_t hs[32 * 512];   // 32KB, XOR-swizzled
  __shared__ alignas(16) bf16_t es[32 * 512];
  __shared__ float red[8][32][2];
  __shared__ float alpha_s[32], fsq_s[32], tgt_s[32];
  __shared__ int notdone_s;

  const int t = threadIdx.x, lane = t & 63, w = t >> 6;
  const int la = lane & 15, lg = lane >> 4;
  const int s_base = blockIdx.x * 32;
  const int arow = lane & 31, ahi = lane >> 5;

  // ---- P0: fbf -> hs (swizzled) + fsq; 16 threads per row
  {
    const int row = t >> 4, c0 = (t & 15) * 4;
    float s = 0.0f;
#pragma unroll
    for (int i = 0; i < 4; ++i) {
      const int k8 = c0 + i;
      bf16x8 v = *(const bf16x8*)(fbf + (size_t)(s_base + row) * ND + k8 * 8);
#pragma unroll
      for (int q = 0; q < 8; ++q) { float f = (float)v[q]; s = fmaf(f, f, s); }
      *(bf16x8*)((char*)hs + (row << 10) + ((k8 ^ (row & 7)) << 4)) = v;
    }
    s += __shfl_xor(s, 1); s += __shfl_xor(s, 2); s += __shfl_xor(s, 4); s += __shfl_xor(s, 8);
    if ((t & 15) == 0) fsq_s[row] = s;
  }
  if (t < 32) {
    alpha_s[t] = 1.0f;
    tgt_s[t] = 0.99f * (yxsq[s_base + t] + 0.01f * xsq[s_base + t]);
  }
  __syncthreads();

  // ---- P1: u0 = fbf @ Wv1; wave w owns HV cols [w*64, w*64+64)
  f32x4 uacc[2][4] = {};   // [mt][nt]
#pragma unroll
  for (int k = 0; k < 16; ++k) {
    bf16x8 afr[2];
#pragma unroll
    for (int mt = 0; mt < 2; ++mt) {
      const int row = mt * 16 + la;
      afr[mt] = *(const bf16x8*)((const char*)hs + (row << 10) + (((k * 4 + lg) ^ (row & 7)) << 4));
    }
#pragma unroll
    for (int nt = 0; nt < 4; ++nt) {
      const bf16x8 b = *(const bf16x8*)(wv1t + (size_t)(w * 64 + nt * 16 + la) * ND + k * 32 + lg * 8);
#pragma unroll
      for (int mt = 0; mt < 2; ++mt)
        uacc[mt][nt] = __builtin_amdgcn_mfma_f32_16x16x32_bf16(afr[mt], b, uacc[mt][nt], 0, 0, 0);
    }
  }

  // ---- P2: deposit u0 -> es in [row][k8] XOR layout (C: col=la, row=lg*4+r)
#pragma unroll
  for (int mt = 0; mt < 2; ++mt)
#pragma unroll
    for (int nt = 0; nt < 4; ++nt)
#pragma unroll
      for (int r = 0; r < 4; ++r) {
        const int row = mt * 16 + lg * 4 + r;
        const int col = w * 64 + nt * 16 + la;
        *(bf16_t*)((char*)es + (row << 10) + (((col >> 3) ^ (row & 7)) << 4) + (col & 7) * 2)
            = (bf16_t)uacc[mt][nt][r];
      }
  __syncthreads();

  // ureg from es (phase-A ownership: row=arow, chunks k8 = w*8+ahi*4+i)
  bf16x8 ureg[4];
#pragma unroll
  for (int i = 0; i < 4; ++i) {
    const int k8 = w * 8 + ahi * 4 + i;
    ureg[i] = *(const bf16x8*)((const char*)es + (arow << 10) + ((k8 ^ (arow & 7)) << 4));
  }

  // Wv2t B-frags -> registers (after u0 phase to keep peak VGPR low)
  bf16x8 bfr[2][16];
#pragma unroll
  for (int nt = 0; nt < 2; ++nt) {
    const bf16_t* bp = Wv2t + (size_t)(w * 32 + nt * 16 + la) * NHV + lg * 8;
#pragma unroll
    for (int k = 0; k < 16; ++k)
      bfr[nt][k] = *(const bf16x8*)(bp + k * 32);
  }
  __syncthreads();   // all ureg reads of es done before phase-A overwrites it

  for (int it = 0; it < NEWTON_MAX; ++it) {
    // ---- phase A: tanh from registers -> swizzled LDS
    {
      const float c2 = 2.0f * alpha_s[arow];
#pragma unroll
      for (int i = 0; i < 4; ++i) {
        const int k8 = w * 8 + ahi * 4 + i;
        const int byte = (arow << 10) + ((k8 ^ (arow & 7)) << 4);
        bf16x8 uv = ureg[i], hf, ef;
#pragma unroll
        for (int q = 0; q < 8; ++q) {
          float u = (float)uv[q];
          float e = __expf(c2 * u);
          float h = (e - 1.0f) * __builtin_amdgcn_rcpf(e + 1.0f);
          hf[q] = (bf16_t)h;
          ef[q] = (bf16_t)(u * (1.0f - h * h));
        }
        *(bf16x8*)((char*)hs + byte) = hf;
        *(bf16x8*)((char*)es + byte) = ef;
      }
    }
    __syncthreads();

    // ---- phase B: MFMA with register-resident B
    f32x4 accy[2][2] = {};
    f32x4 accw[2][2] = {};
#pragma unroll
    for (int k = 0; k < 16; ++k) {
#pragma unroll
      for (int mt = 0; mt < 2; ++mt) {
        const int row = mt * 16 + la;
        const int byte = (row << 10) + (((k * 4 + lg) ^ (row & 7)) << 4);
        bf16x8 hf = *(const bf16x8*)((const char*)hs + byte);
        bf16x8 ef = *(const bf16x8*)((const char*)es + byte);
#pragma unroll
        for (int nt = 0; nt < 2; ++nt) {
          accy[mt][nt] = __builtin_amdgcn_mfma_f32_16x16x32_bf16(hf, bfr[nt][k], accy[mt][nt], 0, 0, 0);
          accw[mt][nt] = __builtin_amdgcn_mfma_f32_16x16x32_bf16(ef, bfr[nt][k], accw[mt][nt], 0, 0, 0);
        }
      }
    }

    // ---- reduce: SY = sum y^2, SW = sum y*w  (C layout: col=la, row=lg*4+r)
#pragma unroll
    for (int mt = 0; mt < 2; ++mt) {
#pragma unroll
      for (int r = 0; r < 4; ++r) {
        float sy = 0.0f, sw = 0.0f;
#pragma unroll
        for (int nt = 0; nt < 2; ++nt) {
          float yv = accy[mt][nt][r], wv = accw[mt][nt][r];
          sy = fmaf(yv, yv, sy);
          sw = fmaf(yv, wv, sw);
        }
        sy += __shfl_xor(sy, 1); sw += __shfl_xor(sw, 1);
        sy += __shfl_xor(sy, 2); sw += __shfl_xor(sw, 2);
        sy += __shfl_xor(sy, 4); sw += __shfl_xor(sw, 4);
        sy += __shfl_xor(sy, 8); sw += __shfl_xor(sw, 8);
        if (la == 0) {
          red[w][mt * 16 + lg * 4 + r][0] = sy;
          red[w][mt * 16 + lg * 4 + r][1] = sw;
        }
      }
    }
    __syncthreads();
    if (t < 32) {
      float SY = 0.0f, SW = 0.0f;
#pragma unroll
      for (int w8 = 0; w8 < 8; ++w8) {
        SY += red[w8][t][0];
        SW += red[w8][t][1];
      }
      float a = alpha_s[t];
      const float fs = fsq_s[t];
      const float V = SY + 0.01f * a * a * fs;
      const float dV = 2.0f * SW + 0.02f * a * fs;
      const float resid = V - tgt_s[t];
      const bool go = resid > RF_TOL;
      if (go) {
        if (it == 0)
          alpha_s[t] = __builtin_sqrtf(tgt_s[t] / V);  // quadratic-model root (a==1, V==V1)
        else
          alpha_s[t] = a - resid / dV;                 // ref's Newton step
      }
      const int nd = __any(go);
      if (t == 0) notdone_s = nd;
    }
    __syncthreads();
    if (!notdone_s) break;                   // all converged: further iters no-op
  }

  // ---- conditional in-place scale: only alpha!=1 rows touch memory.
  // alpha==1 rows: out already holds fhat (G2 wrote it) == fhat*1.0f exactly.
  {
    const int r = t >> 4;
    const int c4 = t & 15;
    const float a = alpha_s[r];
    if (a != 1.0f) {
      const size_t rb = (size_t)(s_base + r) * ND;
      float4* dp = (float4*)(out + rb);
#pragma unroll
      for (int jj = 0; jj < 8; ++jj) {
        float4 v = dp[c4 + jj * 16];
        v.x *= a; v.y *= a; v.z *= a; v.w *= a;
        dp[c4 + jj * 16] = v;
      }
    }
  }
}

extern "C" void kernel_launch(void* const* d_in, const int* in_sizes, int n_in,
                              void* d_out, int out_size, void* d_ws, size_t ws_size,
                              hipStream_t stream)
{
  (void)in_sizes; (void)n_in; (void)out_size; (void)ws_size;
  const float* x   = (const float*)d_in[0];
  const float* W1  = (const float*)d_in[1];
  const float* b1  = (const float*)d_in[2];
  const float* W2  = (const float*)d_in[3];
  const float* b2  = (const float*)d_in[4];
  const float* Wv1 = (const float*)d_in[5];
  const float* Wv2 = (const float*)d_in[6];
  float* out = (float*)d_out;

  char* ws = (char*)d_ws;
  size_t off = 0;
  auto alloc = [&](size_t n) { char* p = ws + off; off += (n + 255) & ~(size_t)255; return p; };

  bf16_t* xbf  = (bf16_t*)alloc((size_t)NB * ND * 2);
  bf16_t* w1t  = (bf16_t*)alloc((size_t)NH * ND * 2);
  bf16_t* w2t  = (bf16_t*)alloc((size_t)ND * NH * 2);
  bf16_t* wv1t = (bf16_t*)alloc((size_t)NHV * ND * 2);
  bf16_t* wv2t = (bf16_t*)alloc((size_t)NVO * NHV * 2);
  bf16_t* h1   = (bf16_t*)alloc((size_t)NB * NH * 2);
  bf16_t* fbf  = (bf16_t*)alloc((size_t)NB * ND * 2);
  bf16_t* hx   = (bf16_t*)alloc((size_t)NB * NHV * 2);
  float*  xsq  = (float*)alloc((size_t)NB * 4);
  float*  yxsq = (float*)alloc((size_t)NB * 4);

  // 1. prep: W1,Wv1 transpose+cast (1280 blocks) + x rowcast + yxsq zero (2048)
  prep_kernel<<<3328, 256, 0, stream>>>(x, xbf, xsq, W1, w1t, Wv1, wv1t, yxsq);

  // 2. G1: h1 = tanh(x@W1+b1) [16 bx] + hx = tanh(x@Wv1) [4 bx]
  //    + 9 bx columns of W2/Wv2 transpose freeloaders (576 blocks x 2 tiles)
  //    grid (29, 64) = 1856 blocks, %8==0 -> bijective XCD swizzle (r15 optimum)
  GJob jh1 { xbf, w1t,  b1,      h1,  nullptr, nullptr, NH,  ND, NH  / 128, 1 };
  GJob jhx { xbf, wv1t, nullptr, hx,  nullptr, nullptr, NHV, ND, NHV / 128, 1 };
  gemm_kernel<128, true, 20><<<dim3(29, NB / 128), 256, 0, stream>>>(jh1, jhx, W2, w2t, Wv2, wv2t);

  // 3. G2: {fbf(bf16), out(f32)} = h1@W2+b2 + yxsq += rowsumsq(hx@Wv2)
  //    out doubles as fhat: newton scales only alpha!=1 rows in place.
  GJob jf  { h1,  w2t,  b2,      fbf, out,     nullptr, ND,  NH, ND  / 128, 0 };
  GJob jy  { hx,  wv2t, nullptr, nullptr, nullptr, yxsq, NVO, NHV, NVO / 128, 0 };
  gemm_kernel<64, true, 0><<<dim3(ND / 128 + NVO / 128, NB / 64), 256, 0, stream>>>(jf, jy, nullptr, nullptr, nullptr, nullptr);

  // 4. fused Newton: u0-GEMM + fsq/tgt + root-find + conditional in-place scale
  newton_kernel<<<NB / 32, 512, 0, stream>>>(fbf, wv1t, wv2t, yxsq, xsq, out);
}